// Round 1
// baseline (177.495 us; speedup 1.0000x reference)
//
#include <hip/hip_runtime.h>
#include <math.h>

// Problem constants (from reference setup_inputs)
#define BATCH 512
#define LEN   16384
#define WIN   5
#define WOUT  (LEN - WIN + 1)   // 16380
#define TPB   128
#define WPT   4                  // windows per thread (WOUT % WPT == 0)
#define WPB   (TPB * WPT)        // 512 windows per block
#define EPT   (WPT + WIN - 1)    // 8 elements per thread

// Kernel 1: register sliding-window, no LDS, no barriers.
// Each thread owns WPT=4 consecutive windows -> loads its 8 elements with
// int4/float4 (inter-thread halo overlap is served by the same cache lines
// the wave already fetched, so HBM bytes are unchanged). Sigmoid computed in
// registers; 5-tap sums per window in registers (same tap order as the
// previously-verified kernel -> bit-identical per-window results).
// Accumulates sum_b d^2 and sum_b msum over a batch chunk, stores float4.
__global__ __launch_bounds__(TPB)
void bcl_partial_kernel(const float* __restrict__ pred,
                        const int*   __restrict__ tgt,
                        const int*   __restrict__ msk,
                        float* __restrict__ part_d2,
                        float* __restrict__ part_ms,
                        int bper) {
    const int j0 = blockIdx.x * WPB + (int)threadIdx.x * WPT;  // first window
    if (j0 >= WOUT) return;      // tail threads (WOUT % WPT == 0 -> all-or-nothing)
    const int b0 = blockIdx.y * bper;

    float accd2[WPT] = {0.f, 0.f, 0.f, 0.f};
    float accms[WPT] = {0.f, 0.f, 0.f, 0.f};

    for (int b = b0; b < b0 + bper; ++b) {
        const size_t base = (size_t)b * LEN + j0;  // j0 % 4 == 0 -> 16B aligned

        const int4 m0 = *(const int4*)(msk + base);
        const int4 m1 = *(const int4*)(msk + base + 4);
        const int4 t0 = *(const int4*)(tgt + base);
        const int4 t1 = *(const int4*)(tgt + base + 4);
        const float4 q0 = *(const float4*)(pred + base * 2);
        const float4 q1 = *(const float4*)(pred + base * 2 + 4);
        const float4 q2 = *(const float4*)(pred + base * 2 + 8);
        const float4 q3 = *(const float4*)(pred + base * 2 + 12);

        float m[EPT], tm[EPT], pm[EPT], p2m[EPT];
        {
            const int mi[EPT] = {m0.x, m0.y, m0.z, m0.w, m1.x, m1.y, m1.z, m1.w};
            const int ti[EPT] = {t0.x, t0.y, t0.z, t0.w, t1.x, t1.y, t1.z, t1.w};
            const float dx[EPT] = {q0.x - q0.y, q0.z - q0.w,
                                   q1.x - q1.y, q1.z - q1.w,
                                   q2.x - q2.y, q2.z - q2.w,
                                   q3.x - q3.y, q3.z - q3.w};
#pragma unroll
            for (int i = 0; i < EPT; ++i) {
                const float p  = 1.0f / (1.0f + __expf(dx[i]));  // softmax[...,1]
                const float mf = (float)mi[i];
                m[i]   = mf;
                tm[i]  = (float)(ti[i] & mi[i]);  // t*m, both in {0,1}
                pm[i]  = p * mf;
                p2m[i] = p * p * mf;
            }
        }

#pragma unroll
        for (int w = 0; w < WPT; ++w) {
            float msum = 0.f, stm = 0.f, spm = 0.f, sp2m = 0.f;
#pragma unroll
            for (int k = 0; k < WIN; ++k) {   // same ascending tap order as before
                msum += m[w + k];
                stm  += tm[w + k];
                spm  += pm[w + k];
                sp2m += p2m[w + k];
            }
            // st2m == stm since t in {0,1}
            const float denom = fmaxf(msum, 1.0f);
            const float inv   = 1.0f / denom;
            const float pmean = spm * inv;
            const float tmean = stm * inv;
            const float pvar  = (sp2m - 2.0f * pmean * spm + pmean * pmean * msum) * inv;
            const float tvar  = (stm  - 2.0f * tmean * stm + tmean * tmean * msum) * inv;
            const float d = pvar - tvar;
            accd2[w] += d * d;
            accms[w] += msum;
        }
    }

    // coalesced float4 stores (WOUT % 4 == 0 keeps rows 16B aligned)
    *(float4*)(part_d2 + (size_t)blockIdx.y * WOUT + j0) =
        make_float4(accd2[0], accd2[1], accd2[2], accd2[3]);
    *(float4*)(part_ms + (size_t)blockIdx.y * WOUT + j0) =
        make_float4(accms[0], accms[1], accms[2], accms[3]);
}

// Kernel 2: per-window reduce over chunks -> mse*valid; block-reduce to
// doubles; atomicAdd into global accumulators; last block finalizes output.
__global__ void bcl_window_reduce(const float* __restrict__ part_d2,
                                  const float* __restrict__ part_ms,
                                  double* __restrict__ accum,  // [num, cnt]
                                  unsigned int* __restrict__ ticket,
                                  float* __restrict__ out,
                                  int nchunks) {
    const int j = blockIdx.x * blockDim.x + threadIdx.x;
    double num = 0.0, cnt = 0.0;
    if (j < WOUT) {
        float d2 = 0.f, ms = 0.f;
        for (int c = 0; c < nchunks; ++c) {   // ascending c == ascending b order
            d2 += part_d2[(size_t)c * WOUT + j];
            ms += part_ms[(size_t)c * WOUT + j];
        }
        if (ms > 0.f) {
            num = (double)d2 * (1.0 / (double)BATCH);
            cnt = 1.0;
        }
    }
    // wave reduce (wave = 64)
    for (int off = 32; off > 0; off >>= 1) {
        num += __shfl_down(num, off, 64);
        cnt += __shfl_down(cnt, off, 64);
    }
    __shared__ double s_num[4], s_cnt[4];
    const int lane = threadIdx.x & 63, wave = threadIdx.x >> 6;
    if (lane == 0) { s_num[wave] = num; s_cnt[wave] = cnt; }
    __syncthreads();
    if (threadIdx.x == 0) {
        double n = 0.0, c = 0.0;
        const int nw = (int)(blockDim.x >> 6);
        for (int wv = 0; wv < nw; ++wv) { n += s_num[wv]; c += s_cnt[wv]; }
        atomicAdd(&accum[0], n);
        atomicAdd(&accum[1], c);
        __threadfence();
        const unsigned int t = atomicAdd(ticket, 1u);
        if (t == gridDim.x - 1) {
            out[0] = (float)(accum[0] / fmax(accum[1], 1.0));
        }
    }
}

extern "C" void kernel_launch(void* const* d_in, const int* in_sizes, int n_in,
                              void* d_out, int out_size, void* d_ws, size_t ws_size,
                              hipStream_t stream) {
    const float* pred = (const float*)d_in[0];
    const int*   tgt  = (const int*)d_in[1];
    const int*   msk  = (const int*)d_in[2];
    float* out = (float*)d_out;

    // Pick largest batch-chunk count that fits in workspace (divides 512).
    int nchunks = 64;
    while (nchunks > 1) {
        size_t need = (size_t)nchunks * WOUT * 2 * sizeof(float) + 64;
        if (need <= ws_size) break;
        nchunks >>= 1;
    }
    const int bper = BATCH / nchunks;

    float* part_d2 = (float*)d_ws;
    float* part_ms = part_d2 + (size_t)nchunks * WOUT;
    // 16-byte-aligned tail region: [double num, double cnt, uint ticket]
    size_t off = ((size_t)nchunks * WOUT * 2 * sizeof(float) + 15) & ~(size_t)15;
    double* accum = (double*)((char*)d_ws + off);
    unsigned int* ticket = (unsigned int*)(accum + 2);

    // zero the accumulators + ticket (ws is re-poisoned every call)
    hipMemsetAsync((void*)accum, 0, 2 * sizeof(double) + sizeof(unsigned int), stream);

    const int WBLKS = (WOUT + WPB - 1) / WPB;  // 32
    dim3 g1(WBLKS, nchunks);
    bcl_partial_kernel<<<g1, TPB, 0, stream>>>(pred, tgt, msk, part_d2, part_ms, bper);

    const int RBLKS = (WOUT + 255) / 256;      // 64
    bcl_window_reduce<<<RBLKS, 256, 0, stream>>>(part_d2, part_ms, accum, ticket, out, nchunks);
}

// Round 2
// 165.999 us; speedup vs baseline: 1.0693x; 1.0693x over previous
//
#include <hip/hip_runtime.h>
#include <math.h>

// Problem constants (from reference setup_inputs)
#define BATCH 512
#define LEN   16384
#define WIN   5
#define WOUT  (LEN - WIN + 1)   // 16380
#define TPB   256
#define WPT   4                  // windows per thread (WOUT % WPT == 0)
#define WPB   (TPB * WPT)        // 1024 windows per block
#define EPT   (WPT + WIN - 1)    // 8 elements per thread
#define NCH2  16                 // stage-A output chunks

// fast reciprocal: v_rcp_f32 + 1 Newton step (~0.5 ulp), ~3 insts vs ~10 for fdiv
__device__ __forceinline__ float fast_rcp(float x) {
    float r = __builtin_amdgcn_rcpf(x);
    return r * fmaf(-x, r, 2.0f);
}

// Kernel 1: register sliding-window, no LDS, no barriers.
// TPB=256, nchunks=128 -> 2048 blocks x 4 waves = 32 waves/CU demand;
// __launch_bounds__(256,8) caps VGPR at 64 so all 8 waves/SIMD stay resident
// and the compiler has room to issue all 12 vector loads before waiting.
__global__ __launch_bounds__(TPB, 8)
void bcl_partial_kernel(const float* __restrict__ pred,
                        const int*   __restrict__ tgt,
                        const int*   __restrict__ msk,
                        float* __restrict__ part_d2,
                        float* __restrict__ part_ms,
                        int bper) {
    const int j0 = blockIdx.x * WPB + (int)threadIdx.x * WPT;  // first window
    if (j0 >= WOUT) return;      // tail threads of last block
    const int b0 = blockIdx.y * bper;

    float accd2[WPT] = {0.f, 0.f, 0.f, 0.f};
    float accms[WPT] = {0.f, 0.f, 0.f, 0.f};

    for (int b = b0; b < b0 + bper; ++b) {
        const size_t base = (size_t)b * LEN + j0;  // j0 % 4 == 0 -> 16B aligned

        const int4 m0 = *(const int4*)(msk + base);
        const int4 m1 = *(const int4*)(msk + base + 4);
        const int4 t0 = *(const int4*)(tgt + base);
        const int4 t1 = *(const int4*)(tgt + base + 4);
        const float4 q0 = *(const float4*)(pred + base * 2);
        const float4 q1 = *(const float4*)(pred + base * 2 + 4);
        const float4 q2 = *(const float4*)(pred + base * 2 + 8);
        const float4 q3 = *(const float4*)(pred + base * 2 + 12);

        float m[EPT], tm[EPT], pm[EPT], p2m[EPT];
        {
            const int mi[EPT] = {m0.x, m0.y, m0.z, m0.w, m1.x, m1.y, m1.z, m1.w};
            const int ti[EPT] = {t0.x, t0.y, t0.z, t0.w, t1.x, t1.y, t1.z, t1.w};
            const float dx[EPT] = {q0.x - q0.y, q0.z - q0.w,
                                   q1.x - q1.y, q1.z - q1.w,
                                   q2.x - q2.y, q2.z - q2.w,
                                   q3.x - q3.y, q3.z - q3.w};
#pragma unroll
            for (int i = 0; i < EPT; ++i) {
                const float p  = fast_rcp(1.0f + __expf(dx[i]));  // softmax[...,1]
                const float mf = (float)mi[i];
                m[i]   = mf;
                tm[i]  = (float)(ti[i] & mi[i]);  // t*m, both in {0,1}
                pm[i]  = p * mf;
                p2m[i] = p * p * mf;
            }
        }

#pragma unroll
        for (int w = 0; w < WPT; ++w) {
            float msum = 0.f, stm = 0.f, spm = 0.f, sp2m = 0.f;
#pragma unroll
            for (int k = 0; k < WIN; ++k) {   // ascending tap order (kept)
                msum += m[w + k];
                stm  += tm[w + k];
                spm  += pm[w + k];
                sp2m += p2m[w + k];
            }
            // st2m == stm since t in {0,1}
            const float denom = fmaxf(msum, 1.0f);
            const float inv   = fast_rcp(denom);
            const float pmean = spm * inv;
            const float tmean = stm * inv;
            const float pvar  = (sp2m - 2.0f * pmean * spm + pmean * pmean * msum) * inv;
            const float tvar  = (stm  - 2.0f * tmean * stm + tmean * tmean * msum) * inv;
            const float d = pvar - tvar;
            accd2[w] += d * d;
            accms[w] += msum;
        }
    }

    // coalesced float4 stores (WOUT % 4 == 0 keeps rows 16B aligned)
    *(float4*)(part_d2 + (size_t)blockIdx.y * WOUT + j0) =
        make_float4(accd2[0], accd2[1], accd2[2], accd2[3]);
    *(float4*)(part_ms + (size_t)blockIdx.y * WOUT + j0) =
        make_float4(accms[0], accms[1], accms[2], accms[3]);
}

// Stage A: fold nchunks -> NCH2 chunk groups. Grid (64, NCH2) = 1024 blocks
// so the fold has real TLP (prev version: 64 blocks walking all chunks ->
// latency-bound, ~100 us hidden cost).
__global__ __launch_bounds__(TPB)
void bcl_chunk_reduce(const float* __restrict__ part_d2,
                      const float* __restrict__ part_ms,
                      float* __restrict__ p2_d2,
                      float* __restrict__ p2_ms,
                      int rf) {
    const int j = blockIdx.x * blockDim.x + threadIdx.x;
    if (j >= WOUT) return;
    const int c0 = blockIdx.y * rf;
    float d2 = 0.f, ms = 0.f;
#pragma unroll 8
    for (int c = c0; c < c0 + rf; ++c) {   // ascending c: deterministic
        d2 += part_d2[(size_t)c * WOUT + j];
        ms += part_ms[(size_t)c * WOUT + j];
    }
    p2_d2[(size_t)blockIdx.y * WOUT + j] = d2;
    p2_ms[(size_t)blockIdx.y * WOUT + j] = ms;
}

// Stage B: fold NCH2 groups -> mse*valid; block-reduce to doubles; atomicAdd
// into global accumulators; last block finalizes output.
__global__ __launch_bounds__(TPB)
void bcl_window_reduce(const float* __restrict__ p2_d2,
                       const float* __restrict__ p2_ms,
                       double* __restrict__ accum,  // [num, cnt]
                       unsigned int* __restrict__ ticket,
                       float* __restrict__ out,
                       int nch2) {
    const int j = blockIdx.x * blockDim.x + threadIdx.x;
    double num = 0.0, cnt = 0.0;
    if (j < WOUT) {
        float d2 = 0.f, ms = 0.f;
#pragma unroll 8
        for (int c = 0; c < nch2; ++c) {   // ascending group order
            d2 += p2_d2[(size_t)c * WOUT + j];
            ms += p2_ms[(size_t)c * WOUT + j];
        }
        if (ms > 0.f) {
            num = (double)d2 * (1.0 / (double)BATCH);
            cnt = 1.0;
        }
    }
    // wave reduce (wave = 64)
    for (int off = 32; off > 0; off >>= 1) {
        num += __shfl_down(num, off, 64);
        cnt += __shfl_down(cnt, off, 64);
    }
    __shared__ double s_num[4], s_cnt[4];
    const int lane = threadIdx.x & 63, wave = threadIdx.x >> 6;
    if (lane == 0) { s_num[wave] = num; s_cnt[wave] = cnt; }
    __syncthreads();
    if (threadIdx.x == 0) {
        double n = 0.0, c = 0.0;
        const int nw = (int)(blockDim.x >> 6);
        for (int wv = 0; wv < nw; ++wv) { n += s_num[wv]; c += s_cnt[wv]; }
        atomicAdd(&accum[0], n);
        atomicAdd(&accum[1], c);
        __threadfence();
        const unsigned int t = atomicAdd(ticket, 1u);
        if (t == gridDim.x - 1) {
            out[0] = (float)(accum[0] / fmax(accum[1], 1.0));
        }
    }
}

extern "C" void kernel_launch(void* const* d_in, const int* in_sizes, int n_in,
                              void* d_out, int out_size, void* d_ws, size_t ws_size,
                              hipStream_t stream) {
    const float* pred = (const float*)d_in[0];
    const int*   tgt  = (const int*)d_in[1];
    const int*   msk  = (const int*)d_in[2];
    float* out = (float*)d_out;

    // Pick largest batch-chunk count that fits in workspace (divides 512).
    int nchunks = 128;
    while (nchunks > 1) {
        size_t need = (size_t)(nchunks + NCH2) * WOUT * 2 * sizeof(float) + 256;
        if (need <= ws_size) break;
        nchunks >>= 1;
    }
    const int bper = BATCH / nchunks;
    const int nch2 = (nchunks >= NCH2) ? NCH2 : nchunks;
    const int rf   = nchunks / nch2;

    float* part_d2 = (float*)d_ws;
    float* part_ms = part_d2 + (size_t)nchunks * WOUT;
    float* p2_d2   = part_ms + (size_t)nchunks * WOUT;
    float* p2_ms   = p2_d2   + (size_t)NCH2 * WOUT;
    // 16-byte-aligned tail region: [double num, double cnt, uint ticket]
    size_t off = ((size_t)((char*)(p2_ms + (size_t)NCH2 * WOUT) - (char*)d_ws) + 15) & ~(size_t)15;
    double* accum = (double*)((char*)d_ws + off);
    unsigned int* ticket = (unsigned int*)(accum + 2);

    // zero the accumulators + ticket (ws is re-poisoned every call)
    hipMemsetAsync((void*)accum, 0, 2 * sizeof(double) + sizeof(unsigned int), stream);

    const int WBLKS = (WOUT + WPB - 1) / WPB;  // 16
    dim3 g1(WBLKS, nchunks);
    bcl_partial_kernel<<<g1, TPB, 0, stream>>>(pred, tgt, msk, part_d2, part_ms, bper);

    const int RBLKS = (WOUT + TPB - 1) / TPB;  // 64
    dim3 gA(RBLKS, nch2);
    bcl_chunk_reduce<<<gA, TPB, 0, stream>>>(part_d2, part_ms, p2_d2, p2_ms, rf);

    bcl_window_reduce<<<RBLKS, TPB, 0, stream>>>(p2_d2, p2_ms, accum, ticket, out, nch2);
}